// Round 11
// baseline (214.792 us; speedup 1.0000x reference)
//
#include <hip/hip_runtime.h>
#include <math.h>

#define N_NODES 100000
#define N_EDGES 1600000
#define NB_BANK 1000
#define N_PAIRS 500000

#define BUCK_SHIFT 8
#define BUCK_NODES 256
#define NBUCK 391            // ceil(N_NODES/256)
#define NSLOT (NBUCK * BUCK_NODES)   // 100096 perm slots
#define BCAP 5504            // fixed ebuf/csr stride per bucket (mean 4092 + 22 sigma)
#define EPB 4096             // edges per scatter block (392 blocks: 1.5/CU)
#define NSCAT 391            // ceil(N_EDGES/EPB)
#define NZB4 489             // ceil(N_PAIRS/(256*4)) : 4 pairs per thread
#define SMASK 0x1FFFF        // low 17 bits = src id (N_NODES < 2^17)
#define ECACHE 11            // ceil(BCAP/512) register-cache slots for degfill

struct Consts {
  float C[27*8];    // [P1|P2] : X -> 8 channels
  float Rb[27*8];   // [Wb@Ttop | Wb@Tbot]
  float u[8];       // coefficient of dvec (A-hat * 1)
  float vg[8];      // graph-row constant
  float vb[8];      // bank-row constant
};

// ---- dense weight-chain precompute, runs as the extra block of k_scatter ----
__device__ void precompute_body(
    const float* __restrict__ W1, const float* __restrict__ b1,
    const float* __restrict__ W2, const float* __restrict__ b2,
    const float* __restrict__ Wb, const float* __restrict__ bb,
    const float* __restrict__ Wf1, const float* __restrict__ bf1,
    const float* __restrict__ Wf2, const float* __restrict__ bf2,
    const float* __restrict__ Wf3, const float* __restrict__ bf3,
    Consts* __restrict__ cst) {
  __shared__ float A[40*4];    // Wf2 @ Wf3
  __shared__ float T[100*4];   // Wf1 @ A
  __shared__ float B[60*8];    // W2 @ [Ttop|Tbot]
  __shared__ float cvec[4];
  const int tid = threadIdx.x;
  const int nt = blockDim.x;

  for (int idx = tid; idx < 160; idx += nt) {
    int r = idx >> 2, k = idx & 3;
    float s = 0.f;
    for (int j = 0; j < 20; ++j) s += Wf2[r*20+j] * Wf3[j*4+k];
    A[idx] = s;
  }
  __syncthreads();
  for (int idx = tid; idx < 400; idx += nt) {
    int r = idx >> 2, k = idx & 3;
    float s = 0.f;
    for (int j = 0; j < 40; ++j) s += Wf1[r*40+j] * A[j*4+k];
    T[idx] = s;
  }
  if (tid < 4) {
    float s = bf3[tid];
    for (int j = 0; j < 40; ++j) s += bf1[j] * A[j*4+tid];
    for (int j = 0; j < 20; ++j) s += bf2[j] * Wf3[j*4+tid];
    cvec[tid] = s;
  }
  __syncthreads();
  for (int idx = tid; idx < 480; idx += nt) {
    int r = idx >> 3, k = idx & 7;
    int half = k >> 2, kk = k & 3;
    float s = 0.f;
    for (int j = 0; j < 50; ++j) s += W2[r*50+j] * T[(half*50+j)*4+kk];
    B[idx] = s;
  }
  __syncthreads();
  for (int idx = tid; idx < 456; idx += nt) {
    if (idx < 216) {                       // C = W1 @ B [27,8]
      int r = idx >> 3, k = idx & 7;
      float s = 0.f;
      for (int j = 0; j < 60; ++j) s += W1[r*60+j] * B[j*8+k];
      cst->C[idx] = s;
    } else if (idx < 432) {                // Rb = Wb @ [Ttop|Tbot] [27,8]
      int i2 = idx - 216;
      int r = i2 >> 3, k = i2 & 7, half = k >> 2, kk = k & 3;
      float s = 0.f;
      for (int j = 0; j < 50; ++j) s += Wb[r*50+j] * T[(half*50+j)*4+kk];
      cst->Rb[i2] = s;
    } else if (idx < 440) {                // u = b1 @ B
      int k = idx - 432;
      float s = 0.f;
      for (int j = 0; j < 60; ++j) s += b1[j] * B[j*8+k];
      cst->u[k] = s;
    } else if (idx < 448) {                // vg = b2 @ [Ttop|Tbot] (+c on half 0)
      int k = idx - 440, half = k >> 2, kk = k & 3;
      float s = (half == 0) ? cvec[kk] : 0.f;
      for (int j = 0; j < 50; ++j) s += b2[j] * T[(half*50+j)*4+kk];
      cst->vg[k] = s;
    } else {                               // vb = bb @ [Ttop|Tbot] (+c on half 0)
      int k = idx - 448, half = k >> 2, kk = k & 3;
      float s = (half == 0) ? cvec[kk] : 0.f;
      for (int j = 0; j < 50; ++j) s += bb[j] * T[(half*50+j)*4+kk];
      cst->vb[k] = s;
    }
  }
}

// --- single-pass bucket scatter; BOTH src and dst register-cached ------------
__global__ __launch_bounds__(1024) void k_scatter(
    const int* __restrict__ ei, int* __restrict__ bcnt, int* __restrict__ ebuf,
    const float* __restrict__ W1, const float* __restrict__ b1,
    const float* __restrict__ W2, const float* __restrict__ b2,
    const float* __restrict__ Wb, const float* __restrict__ bb,
    const float* __restrict__ Wf1, const float* __restrict__ bf1,
    const float* __restrict__ Wf2, const float* __restrict__ bf2,
    const float* __restrict__ Wf3, const float* __restrict__ bf3,
    Consts* __restrict__ cst) {
  if (blockIdx.x == NSCAT) {   // whole-block branch: safe with __syncthreads
    precompute_body(W1, b1, W2, b2, Wb, bb, Wf1, bf1, Wf2, bf2, Wf3, bf3, cst);
    return;
  }
  __shared__ int hist[NBUCK];
  __shared__ int base[NBUCK];
  const int t = threadIdx.x;
  const int e0 = blockIdx.x * EPB;
  int dcache[EPB / 1024];
  int scache[EPB / 1024];
  if (t < NBUCK) hist[t] = 0;
  __syncthreads();
#pragma unroll
  for (int i = 0; i < EPB / 1024; ++i) {
    int e = e0 + i * 1024 + t;
    int d = -1, s = 0;
    if (e < N_EDGES) { d = ei[N_EDGES + e]; s = ei[e]; }
    dcache[i] = d;
    scache[i] = s;
    if (d >= 0) atomicAdd(&hist[d >> BUCK_SHIFT], 1);
  }
  __syncthreads();
  if (t < NBUCK) {
    int h = hist[t];
    base[t] = h ? (t * BCAP + atomicAdd(&bcnt[t], h)) : 0;
    hist[t] = 0;
  }
  __syncthreads();
#pragma unroll
  for (int i = 0; i < EPB / 1024; ++i) {
    int d = dcache[i];
    if (d >= 0) {
      int b = d >> BUCK_SHIFT;
      int pos = base[b] + atomicAdd(&hist[b], 1);
      ebuf[pos] = ((d & (BUCK_NODES - 1)) << 17) | scache[i];
    }
  }
}

// -- per-bucket: degree/dinv/rbeg/rend + CSR fill + fused Xs + degree-sorted --
// perm: within each bucket, nodes are counting-sorted by degree so that the
// 16 nodes a gather wave covers have near-identical degrees (no wave-max tail).
__global__ __launch_bounds__(512) void k_degfill_x8(
    const int* __restrict__ bcnt, const int* __restrict__ ebuf,
    const float* __restrict__ x, const Consts* __restrict__ cst,
    float* __restrict__ dinv, int* __restrict__ rbeg, int* __restrict__ rend,
    int* __restrict__ csr, float* __restrict__ Xs, int* __restrict__ perm) {
  __shared__ int cnt[BUCK_NODES];
  __shared__ int lcur[BUCK_NODES];
  __shared__ float sdinv[BUCK_NODES];
  __shared__ float xs[BUCK_NODES * 27];     // 27.6 KB (total ~31 KB)
  const int b = blockIdx.x;
  const int t = threadIdx.x;
  int ecache[ECACHE];                       // register-cached ebuf codes
  if (t < BUCK_NODES) cnt[t] = 0;
  __syncthreads();
  const int beg = b * BCAP, end = beg + bcnt[b];
  int ne = 0;
  for (int j = beg + t; j < end; j += 512, ++ne) {
    int code = ebuf[j];
    ecache[ne] = code;
    atomicAdd(&cnt[code >> 17], 1);
  }
  // stage x rows for this bucket (independent work, overlaps count pass)
  const int xbase = b * (BUCK_NODES * 27);
  for (int j = t; j < BUCK_NODES * 27; j += 512) {
    int g = xbase + j;
    xs[j] = (g < N_NODES * 27) ? x[g] : 0.f;
  }
  __syncthreads();
  int v = (t < BUCK_NODES) ? cnt[t] : 0;    // this node's degree (stays live)
  // Hillis-Steele inclusive scan over 256 (threads >=256 idle but hit barriers)
  for (int off = 1; off < BUCK_NODES; off <<= 1) {
    int u = (t < BUCK_NODES && t >= off) ? cnt[t - off] : 0;
    __syncthreads();
    if (t < BUCK_NODES) cnt[t] += u;
    __syncthreads();
  }
  if (t < BUCK_NODES) {
    const int node = (b << BUCK_SHIFT) + t;
    const int excl = beg + cnt[t] - v;   // start within this bucket's csr range
    lcur[t] = excl;
    float dv = rsqrtf((float)v + 1.0f);  // +1 self-loop
    sdinv[t] = dv;
    if (node < N_NODES) {
      rbeg[node] = excl;
      rend[node] = excl + v;
      dinv[node] = dv;
    }
  }
  __syncthreads();
  for (int i = 0; i < ne; ++i) {
    int code = ecache[i];
    int pos = atomicAdd(&lcur[code >> 17], 1);
    csr[pos] = code & SMASK;
  }
  __syncthreads();                          // lcur free -> reuse for degree sort
  // ---- within-bucket degree counting-sort -> perm --------------------------
  if (t < 64) lcur[t] = 0;
  __syncthreads();
  int cls = 0, lrank = 0;
  if (t < BUCK_NODES) {
    cls = v < 63 ? v : 63;
    lrank = atomicAdd(&lcur[cls], 1);       // rank within degree class
  }
  __syncthreads();
  if (t == 0) {                             // exclusive prefix over 64 classes
    int run = 0;
    for (int i = 0; i < 64; ++i) { int c = lcur[i]; lcur[i] = run; run += c; }
  }
  __syncthreads();
  if (t < BUCK_NODES) {
    int node = (b << BUCK_SHIFT) + t;
    int pos = lcur[cls] + lrank;
    perm[(b << BUCK_SHIFT) + pos] = (node < N_NODES) ? node : N_NODES;
  }
  // fused Xs = (x @ C) * dinv for this bucket's 256 nodes
  for (int idx = t; idx < BUCK_NODES * 8; idx += 512) {
    int li = idx >> 3, k = idx & 7;
    int node = (b << BUCK_SHIFT) + li;
    if (node < N_NODES) {
      float s = 0.f;
      for (int c = 0; c < 27; ++c) s += xs[li*27+c] * cst->C[c*8+k];
      Xs[(size_t)node*8+k] = s * sdinv[li];
    }
  }
}

// ------ gather pass 1: degree-sorted node order via perm ---------------------
__global__ __launch_bounds__(256) void k_gather1(const int* __restrict__ perm,
                                                 const int* __restrict__ rbeg,
                                                 const int* __restrict__ rend,
                                                 const int* __restrict__ csr,
                                                 const float* __restrict__ dinv,
                                                 const float2* __restrict__ Xs2,
                                                 float2* __restrict__ Ys2,
                                                 float* __restrict__ dvec) {
  int t = blockIdx.x * 256 + threadIdx.x;
  int slot = t >> 2, q = t & 3;
  if (slot >= NSLOT) return;
  int d = perm[slot];
  if (d >= N_NODES) return;                 // pad sentinel
  const int beg = rbeg[d], end = rend[d];
  const float nd = dinv[d];
  float2 self = Xs2[d*4 + q];
  float ax = self.x, ay = self.y;
  float dsum = nd;                  // self-loop contribution
  int j = beg;
  if (j + 8 <= end) {
    int s0 = csr[j],   s1 = csr[j+1], s2 = csr[j+2], s3 = csr[j+3];
    int s4 = csr[j+4], s5 = csr[j+5], s6 = csr[j+6], s7 = csr[j+7];
    for (;;) {
      float2 a0 = Xs2[s0*4+q], a1 = Xs2[s1*4+q], a2 = Xs2[s2*4+q], a3 = Xs2[s3*4+q];
      float2 a4 = Xs2[s4*4+q], a5 = Xs2[s5*4+q], a6 = Xs2[s6*4+q], a7 = Xs2[s7*4+q];
      float d0 = 0.f, d1 = 0.f, d2 = 0.f, d3 = 0.f;
      float d4 = 0.f, d5 = 0.f, d6 = 0.f, d7 = 0.f;
      if (q == 0) {
        d0 = dinv[s0]; d1 = dinv[s1]; d2 = dinv[s2]; d3 = dinv[s3];
        d4 = dinv[s4]; d5 = dinv[s5]; d6 = dinv[s6]; d7 = dinv[s7];
      }
      int jn = j + 8;
      bool more = (jn + 8 <= end);
      int u0, u1, u2, u3, u4, u5, u6, u7;
      if (more) {
        u0 = csr[jn];   u1 = csr[jn+1]; u2 = csr[jn+2]; u3 = csr[jn+3];
        u4 = csr[jn+4]; u5 = csr[jn+5]; u6 = csr[jn+6]; u7 = csr[jn+7];
      } else {
        u0 = u1 = u2 = u3 = u4 = u5 = u6 = u7 = 0;
      }
      ax += ((a0.x + a1.x) + (a2.x + a3.x)) + ((a4.x + a5.x) + (a6.x + a7.x));
      ay += ((a0.y + a1.y) + (a2.y + a3.y)) + ((a4.y + a5.y) + (a6.y + a7.y));
      if (q == 0)
        dsum += ((d0 + d1) + (d2 + d3)) + ((d4 + d5) + (d6 + d7));
      j = jn;
      if (!more) break;
      s0 = u0; s1 = u1; s2 = u2; s3 = u3;
      s4 = u4; s5 = u5; s6 = u6; s7 = u7;
    }
  }
  if (j + 4 <= end) {               // 4-wide sub-batch shortens the serial tail
    int a = csr[j], b = csr[j+1], c = csr[j+2], e = csr[j+3];
    float2 p0 = Xs2[a*4+q], p1 = Xs2[b*4+q], p2 = Xs2[c*4+q], p3 = Xs2[e*4+q];
    ax += (p0.x + p1.x) + (p2.x + p3.x);
    ay += (p0.y + p1.y) + (p2.y + p3.y);
    if (q == 0) dsum += (dinv[a] + dinv[b]) + (dinv[c] + dinv[e]);
    j += 4;
  }
  for (; j < end; ++j) {
    int s = csr[j];
    float2 a = Xs2[s*4+q];
    ax += a.x; ay += a.y;
    if (q == 0) dsum += dinv[s];
  }
  float nn = nd * nd;
  Ys2[d*4 + q] = make_float2(nn * ax, nn * ay);  // = n_d * h1 (pre-scaled)
  if (q == 0) dvec[d] = nd * dsum;
}

// ------ gather pass 2 (+bank rows past the perm range) -----------------------
__global__ __launch_bounds__(256) void k_gather2g(const int* __restrict__ perm,
                                                  const int* __restrict__ rbeg,
                                                  const int* __restrict__ rend,
                                                  const int* __restrict__ csr,
                                                  const float* __restrict__ dinv,
                                                  const float2* __restrict__ Ys2,
                                                  const float* __restrict__ dvec,
                                                  const float* __restrict__ bank,
                                                  const Consts* __restrict__ cst,
                                                  float2* __restrict__ gall2) {
  int t = blockIdx.x * 256 + threadIdx.x;
  int slot = t >> 2, q = t & 3;
  if (slot >= NSLOT + NB_BANK) return;
  int c0 = 2*q, c1 = 2*q + 1;
  if (slot >= NSLOT) {              // bank rows (unpermuted)
    int bk = slot - NSLOT;
    float sx = cst->vb[c0], sy = cst->vb[c1];
    for (int cc = 0; cc < 27; ++cc) {
      float bv = bank[bk*27+cc];
      sx += bv * cst->Rb[cc*8+c0];
      sy += bv * cst->Rb[cc*8+c1];
    }
    gall2[((size_t)(N_NODES + bk))*4 + q] = make_float2(sx, sy);
    return;
  }
  int d = perm[slot];
  if (d >= N_NODES) return;         // pad sentinel
  const int beg = rbeg[d], end = rend[d];
  float2 self = Ys2[d*4 + q];
  float ax = self.x, ay = self.y;
  int j = beg;
  if (j + 8 <= end) {
    int s0 = csr[j],   s1 = csr[j+1], s2 = csr[j+2], s3 = csr[j+3];
    int s4 = csr[j+4], s5 = csr[j+5], s6 = csr[j+6], s7 = csr[j+7];
    for (;;) {
      float2 a0 = Ys2[s0*4+q], a1 = Ys2[s1*4+q], a2 = Ys2[s2*4+q], a3 = Ys2[s3*4+q];
      float2 a4 = Ys2[s4*4+q], a5 = Ys2[s5*4+q], a6 = Ys2[s6*4+q], a7 = Ys2[s7*4+q];
      int jn = j + 8;
      bool more = (jn + 8 <= end);
      int u0, u1, u2, u3, u4, u5, u6, u7;
      if (more) {
        u0 = csr[jn];   u1 = csr[jn+1]; u2 = csr[jn+2]; u3 = csr[jn+3];
        u4 = csr[jn+4]; u5 = csr[jn+5]; u6 = csr[jn+6]; u7 = csr[jn+7];
      } else {
        u0 = u1 = u2 = u3 = u4 = u5 = u6 = u7 = 0;
      }
      ax += ((a0.x + a1.x) + (a2.x + a3.x)) + ((a4.x + a5.x) + (a6.x + a7.x));
      ay += ((a0.y + a1.y) + (a2.y + a3.y)) + ((a4.y + a5.y) + (a6.y + a7.y));
      j = jn;
      if (!more) break;
      s0 = u0; s1 = u1; s2 = u2; s3 = u3;
      s4 = u4; s5 = u5; s6 = u6; s7 = u7;
    }
  }
  if (j + 4 <= end) {
    int a = csr[j], b = csr[j+1], c = csr[j+2], e = csr[j+3];
    float2 p0 = Ys2[a*4+q], p1 = Ys2[b*4+q], p2 = Ys2[c*4+q], p3 = Ys2[e*4+q];
    ax += (p0.x + p1.x) + (p2.x + p3.x);
    ay += (p0.y + p1.y) + (p2.y + p3.y);
    j += 4;
  }
  for (; j < end; ++j) {
    float2 a = Ys2[csr[j]*4+q];
    ax += a.x; ay += a.y;
  }
  float nd = dinv[d], dv = dvec[d];
  gall2[d*4 + q] = make_float2(nd * ax + dv * cst->u[c0] + cst->vg[c0],
                               nd * ay + dv * cst->u[c1] + cst->vg[c1]);
}

// ---------------- online-softmax merge helper --------------------------------
__device__ inline void sm_merge(float4& m1, float4& s1,
                                const float4 m2, const float4 s2) {
  float4 M;
  M.x = fmaxf(m1.x, m2.x); M.y = fmaxf(m1.y, m2.y);
  M.z = fmaxf(m1.z, m2.z); M.w = fmaxf(m1.w, m2.w);
  s1.x = s1.x * expf(m1.x - M.x) + s2.x * expf(m2.x - M.x);
  s1.y = s1.y * expf(m1.y - M.y) + s2.y * expf(m2.y - M.y);
  s1.z = s1.z * expf(m1.z - M.z) + s2.z * expf(m2.z - M.z);
  s1.w = s1.w * expf(m1.w - M.w) + s2.w * expf(m2.w - M.w);
  m1 = M;
}

// ---- pair stats only (no z materialization); 4 pairs/thread, 489 blocks -----
__global__ __launch_bounds__(256) void k_z(const int* __restrict__ node1,
                                           const int* __restrict__ node2,
                                           const float* __restrict__ gall,
                                           float4* __restrict__ bs_m,
                                           float4* __restrict__ bs_s) {
  const int S = NZB4 * 256;
  int p0 = blockIdx.x * 256 + threadIdx.x;
  float4 m = make_float4(-1e30f, -1e30f, -1e30f, -1e30f);
  float4 s = make_float4(0.f, 0.f, 0.f, 0.f);
#pragma unroll
  for (int i = 0; i < 4; ++i) {
    int p = p0 + i * S;
    if (p < N_PAIRS) {
      int n1 = node1[p], n2 = node2[p];
      const float4 a = *(const float4*)(gall + (size_t)n1*8);
      const float4 b = *(const float4*)(gall + (size_t)n2*8 + 4);
      float4 zv = make_float4(a.x+b.x, a.y+b.y, a.z+b.z, a.w+b.w);
      sm_merge(m, s, zv, make_float4(1.f, 1.f, 1.f, 1.f));
    }
  }
  __shared__ float4 lm[256], ls[256];
  lm[threadIdx.x] = m; ls[threadIdx.x] = s;
  __syncthreads();
  for (int st = 128; st > 0; st >>= 1) {
    if (threadIdx.x < st) {
      float4 mm = lm[threadIdx.x], ss = ls[threadIdx.x];
      sm_merge(mm, ss, lm[threadIdx.x + st], ls[threadIdx.x + st]);
      lm[threadIdx.x] = mm; ls[threadIdx.x] = ss;
    }
    __syncthreads();
  }
  if (threadIdx.x == 0) { bs_m[blockIdx.x] = lm[0]; bs_s[blockIdx.x] = ls[0]; }
}

// -- combine stats (redundant per block) + recompute z from gall + normalize --
__global__ __launch_bounds__(256) void k_final(const int* __restrict__ node1,
                                               const int* __restrict__ node2,
                                               const float* __restrict__ gall,
                                               const float4* __restrict__ bs_m,
                                               const float4* __restrict__ bs_s,
                                               float* __restrict__ out) {
  float4 m = make_float4(-1e30f, -1e30f, -1e30f, -1e30f);
  float4 s = make_float4(0.f, 0.f, 0.f, 0.f);
  for (int i = threadIdx.x; i < NZB4; i += 256)
    sm_merge(m, s, bs_m[i], bs_s[i]);
  __shared__ float4 lm[256], ls[256];
  lm[threadIdx.x] = m; ls[threadIdx.x] = s;
  __syncthreads();
  for (int st = 128; st > 0; st >>= 1) {
    if (threadIdx.x < st) {
      float4 mm = lm[threadIdx.x], ss = ls[threadIdx.x];
      sm_merge(mm, ss, lm[threadIdx.x + st], ls[threadIdx.x + st]);
      lm[threadIdx.x] = mm; ls[threadIdx.x] = ss;
    }
    __syncthreads();
  }
  const float4 M = lm[0], S4 = ls[0];
  const float i0 = 1.f / S4.x, i1 = 1.f / S4.y;
  const float i2 = 1.f / S4.z, i3 = 1.f / S4.w;
  const int S = NZB4 * 256;
  int p0 = blockIdx.x * 256 + threadIdx.x;
#pragma unroll
  for (int i = 0; i < 4; ++i) {
    int p = p0 + i * S;
    if (p < N_PAIRS) {
      int n1 = node1[p], n2 = node2[p];
      const float4 a = *(const float4*)(gall + (size_t)n1*8);
      const float4 b = *(const float4*)(gall + (size_t)n2*8 + 4);
      float4 zv = make_float4(a.x+b.x, a.y+b.y, a.z+b.z, a.w+b.w);
      float4 o = make_float4(expf(zv.x - M.x) * i0, expf(zv.y - M.y) * i1,
                             expf(zv.z - M.z) * i2, expf(zv.w - M.w) * i3);
      ((float4*)out)[p] = o;
    }
  }
}

extern "C" void kernel_launch(void* const* d_in, const int* in_sizes, int n_in,
                              void* d_out, int out_size, void* d_ws, size_t ws_size,
                              hipStream_t stream) {
  const float* x    = (const float*)d_in[0];
  const float* bank = (const float*)d_in[1];
  const float* W1   = (const float*)d_in[2];
  const float* b1   = (const float*)d_in[3];
  const float* W2   = (const float*)d_in[4];
  const float* b2   = (const float*)d_in[5];
  const float* Wb   = (const float*)d_in[6];
  const float* bb   = (const float*)d_in[7];
  const float* Wf1  = (const float*)d_in[8];
  const float* bf1  = (const float*)d_in[9];
  const float* Wf2  = (const float*)d_in[10];
  const float* bf2  = (const float*)d_in[11];
  const float* Wf3  = (const float*)d_in[12];
  const float* bf3  = (const float*)d_in[13];
  const int* ei     = (const int*)d_in[14];
  const int* node1  = (const int*)d_in[15];
  const int* node2  = (const int*)d_in[16];
  float* out = (float*)d_out;

  char* w = (char*)d_ws;
  size_t off = 0;
  auto take = [&](size_t bytes) -> char* {
    char* p = w + off;
    off = (off + bytes + 255) & ~(size_t)255;
    return p;
  };
  Consts* cst    = (Consts*)take(sizeof(Consts));
  int*    bcnt   = (int*)take(NBUCK * 4);
  float*  dinv   = (float*)take(N_NODES * 4);
  int*    rbeg   = (int*)take(N_NODES * 4);
  int*    rend   = (int*)take(N_NODES * 4);
  int*    csr    = (int*)take((size_t)NBUCK * BCAP * 4);
  float*  Xs     = (float*)take((size_t)N_NODES * 8 * 4);
  float*  Ys     = (float*)take((size_t)N_NODES * 8 * 4);
  float*  dvec   = (float*)take(N_NODES * 4);
  float*  gall   = (float*)take((size_t)(N_NODES + NB_BANK) * 8 * 4);
  int*    ebuf   = (int*)take((size_t)NBUCK * BCAP * 4);
  int*    perm   = (int*)take((size_t)NSLOT * 4);
  float4* bs_m   = (float4*)take((size_t)NZB4 * 16);
  float4* bs_s   = (float4*)take((size_t)NZB4 * 16);

  hipMemsetAsync(bcnt, 0, NBUCK * 4, stream);

  // single-pass bucket scatter + (extra block) weight-chain precompute
  k_scatter<<<NSCAT + 1, 1024, 0, stream>>>(ei, bcnt, ebuf, W1, b1, W2, b2,
                                            Wb, bb, Wf1, bf1, Wf2, bf2,
                                            Wf3, bf3, cst);
  // per-bucket: degree/dinv/rbeg/rend + CSR fill + fused Xs + degree-sort perm
  k_degfill_x8<<<NBUCK, 512, 0, stream>>>(bcnt, ebuf, x, cst,
                                          dinv, rbeg, rend, csr, Xs, perm);
  // propagation: degree-uniform waves via perm (software-pipelined csr fetch)
  k_gather1<<<(NSLOT * 4 + 255) / 256, 256, 0, stream>>>(
      perm, rbeg, rend, csr, dinv, (const float2*)Xs, (float2*)Ys, dvec);
  k_gather2g<<<((NSLOT + NB_BANK) * 4 + 255) / 256, 256, 0, stream>>>(
      perm, rbeg, rend, csr, dinv, (const float2*)Ys, dvec, bank, cst,
      (float2*)gall);
  // pair phase: stats only, then combine+recompute-z+normalize (no z buffer)
  k_z<<<NZB4, 256, 0, stream>>>(node1, node2, gall, bs_m, bs_s);
  k_final<<<NZB4, 256, 0, stream>>>(node1, node2, gall, bs_m, bs_s, out);
}

// Round 12
// 199.814 us; speedup vs baseline: 1.0750x; 1.0750x over previous
//
#include <hip/hip_runtime.h>
#include <math.h>

#define N_NODES 100000
#define N_EDGES 1600000
#define NB_BANK 1000
#define N_PAIRS 500000

#define BUCK_SHIFT 8
#define BUCK_NODES 256
#define NBUCK 391            // ceil(N_NODES/256)
#define BCAP 5504            // fixed ebuf/csr stride per bucket (mean 4092 + 22 sigma)
#define EPB 4096             // edges per scatter block (392 blocks: 1.5/CU)
#define NSCAT 391            // ceil(N_EDGES/EPB)
#define NZB4 489             // ceil(N_PAIRS/(256*4)) : 4 pairs per thread
#define SMASK 0x1FFFF        // low 17 bits = src id (N_NODES < 2^17)
#define ECACHE 11            // ceil(BCAP/512) register-cache slots for degfill

struct Consts {
  float C[27*8];    // [P1|P2] : X -> 8 channels
  float Rb[27*8];   // [Wb@Ttop | Wb@Tbot]
  float u[8];       // coefficient of dvec (A-hat * 1)
  float vg[8];      // graph-row constant
  float vb[8];      // bank-row constant
};

// ---- dense weight-chain precompute, runs as the extra block of k_scatter ----
__device__ void precompute_body(
    const float* __restrict__ W1, const float* __restrict__ b1,
    const float* __restrict__ W2, const float* __restrict__ b2,
    const float* __restrict__ Wb, const float* __restrict__ bb,
    const float* __restrict__ Wf1, const float* __restrict__ bf1,
    const float* __restrict__ Wf2, const float* __restrict__ bf2,
    const float* __restrict__ Wf3, const float* __restrict__ bf3,
    Consts* __restrict__ cst) {
  __shared__ float A[40*4];    // Wf2 @ Wf3
  __shared__ float T[100*4];   // Wf1 @ A
  __shared__ float B[60*8];    // W2 @ [Ttop|Tbot]
  __shared__ float cvec[4];
  const int tid = threadIdx.x;
  const int nt = blockDim.x;

  for (int idx = tid; idx < 160; idx += nt) {
    int r = idx >> 2, k = idx & 3;
    float s = 0.f;
    for (int j = 0; j < 20; ++j) s += Wf2[r*20+j] * Wf3[j*4+k];
    A[idx] = s;
  }
  __syncthreads();
  for (int idx = tid; idx < 400; idx += nt) {
    int r = idx >> 2, k = idx & 3;
    float s = 0.f;
    for (int j = 0; j < 40; ++j) s += Wf1[r*40+j] * A[j*4+k];
    T[idx] = s;
  }
  if (tid < 4) {
    float s = bf3[tid];
    for (int j = 0; j < 40; ++j) s += bf1[j] * A[j*4+tid];
    for (int j = 0; j < 20; ++j) s += bf2[j] * Wf3[j*4+tid];
    cvec[tid] = s;
  }
  __syncthreads();
  for (int idx = tid; idx < 480; idx += nt) {
    int r = idx >> 3, k = idx & 7;
    int half = k >> 2, kk = k & 3;
    float s = 0.f;
    for (int j = 0; j < 50; ++j) s += W2[r*50+j] * T[(half*50+j)*4+kk];
    B[idx] = s;
  }
  __syncthreads();
  for (int idx = tid; idx < 456; idx += nt) {
    if (idx < 216) {                       // C = W1 @ B [27,8]
      int r = idx >> 3, k = idx & 7;
      float s = 0.f;
      for (int j = 0; j < 60; ++j) s += W1[r*60+j] * B[j*8+k];
      cst->C[idx] = s;
    } else if (idx < 432) {                // Rb = Wb @ [Ttop|Tbot] [27,8]
      int i2 = idx - 216;
      int r = i2 >> 3, k = i2 & 7, half = k >> 2, kk = k & 3;
      float s = 0.f;
      for (int j = 0; j < 50; ++j) s += Wb[r*50+j] * T[(half*50+j)*4+kk];
      cst->Rb[i2] = s;
    } else if (idx < 440) {                // u = b1 @ B
      int k = idx - 432;
      float s = 0.f;
      for (int j = 0; j < 60; ++j) s += b1[j] * B[j*8+k];
      cst->u[k] = s;
    } else if (idx < 448) {                // vg = b2 @ [Ttop|Tbot] (+c on half 0)
      int k = idx - 440, half = k >> 2, kk = k & 3;
      float s = (half == 0) ? cvec[kk] : 0.f;
      for (int j = 0; j < 50; ++j) s += b2[j] * T[(half*50+j)*4+kk];
      cst->vg[k] = s;
    } else {                               // vb = bb @ [Ttop|Tbot] (+c on half 0)
      int k = idx - 448, half = k >> 2, kk = k & 3;
      float s = (half == 0) ? cvec[kk] : 0.f;
      for (int j = 0; j < 50; ++j) s += bb[j] * T[(half*50+j)*4+kk];
      cst->vb[k] = s;
    }
  }
}

// --- single-pass bucket scatter; BOTH src and dst register-cached ------------
__global__ __launch_bounds__(1024) void k_scatter(
    const int* __restrict__ ei, int* __restrict__ bcnt, int* __restrict__ ebuf,
    const float* __restrict__ W1, const float* __restrict__ b1,
    const float* __restrict__ W2, const float* __restrict__ b2,
    const float* __restrict__ Wb, const float* __restrict__ bb,
    const float* __restrict__ Wf1, const float* __restrict__ bf1,
    const float* __restrict__ Wf2, const float* __restrict__ bf2,
    const float* __restrict__ Wf3, const float* __restrict__ bf3,
    Consts* __restrict__ cst) {
  if (blockIdx.x == NSCAT) {   // whole-block branch: safe with __syncthreads
    precompute_body(W1, b1, W2, b2, Wb, bb, Wf1, bf1, Wf2, bf2, Wf3, bf3, cst);
    return;
  }
  __shared__ int hist[NBUCK];
  __shared__ int base[NBUCK];
  const int t = threadIdx.x;
  const int e0 = blockIdx.x * EPB;
  int dcache[EPB / 1024];
  int scache[EPB / 1024];
  if (t < NBUCK) hist[t] = 0;
  __syncthreads();
#pragma unroll
  for (int i = 0; i < EPB / 1024; ++i) {
    int e = e0 + i * 1024 + t;
    int d = -1, s = 0;
    if (e < N_EDGES) { d = ei[N_EDGES + e]; s = ei[e]; }
    dcache[i] = d;
    scache[i] = s;
    if (d >= 0) atomicAdd(&hist[d >> BUCK_SHIFT], 1);
  }
  __syncthreads();
  if (t < NBUCK) {
    int h = hist[t];
    base[t] = h ? (t * BCAP + atomicAdd(&bcnt[t], h)) : 0;
    hist[t] = 0;
  }
  __syncthreads();
#pragma unroll
  for (int i = 0; i < EPB / 1024; ++i) {
    int d = dcache[i];
    if (d >= 0) {
      int b = d >> BUCK_SHIFT;
      int pos = base[b] + atomicAdd(&hist[b], 1);
      ebuf[pos] = ((d & (BUCK_NODES - 1)) << 17) | scache[i];
    }
  }
}

// -- per-bucket: degree/dinv/rbeg/rend + CSR fill + fused Xs; ebuf read ONCE --
__global__ __launch_bounds__(512) void k_degfill_x8(
    const int* __restrict__ bcnt, const int* __restrict__ ebuf,
    const float* __restrict__ x, const Consts* __restrict__ cst,
    float* __restrict__ dinv, int* __restrict__ rbeg, int* __restrict__ rend,
    int* __restrict__ csr, float* __restrict__ Xs) {
  __shared__ int cnt[BUCK_NODES];
  __shared__ int lcur[BUCK_NODES];
  __shared__ float sdinv[BUCK_NODES];
  __shared__ float xs[BUCK_NODES * 27];     // 27.6 KB (total ~31 KB)
  const int b = blockIdx.x;
  const int t = threadIdx.x;
  int ecache[ECACHE];                       // register-cached ebuf codes
  if (t < BUCK_NODES) cnt[t] = 0;
  __syncthreads();
  const int beg = b * BCAP, end = beg + bcnt[b];
  int ne = 0;
  for (int j = beg + t; j < end; j += 512, ++ne) {
    int code = ebuf[j];
    ecache[ne] = code;
    atomicAdd(&cnt[code >> 17], 1);
  }
  // stage x rows for this bucket (independent work, overlaps count pass)
  const int xbase = b * (BUCK_NODES * 27);
  for (int j = t; j < BUCK_NODES * 27; j += 512) {
    int g = xbase + j;
    xs[j] = (g < N_NODES * 27) ? x[g] : 0.f;
  }
  __syncthreads();
  int v = (t < BUCK_NODES) ? cnt[t] : 0;
  // Hillis-Steele inclusive scan over 256 (threads >=256 idle but hit barriers)
  for (int off = 1; off < BUCK_NODES; off <<= 1) {
    int u = (t < BUCK_NODES && t >= off) ? cnt[t - off] : 0;
    __syncthreads();
    if (t < BUCK_NODES) cnt[t] += u;
    __syncthreads();
  }
  if (t < BUCK_NODES) {
    const int node = (b << BUCK_SHIFT) + t;
    const int excl = beg + cnt[t] - v;   // start within this bucket's csr range
    lcur[t] = excl;
    float dv = rsqrtf((float)v + 1.0f);  // +1 self-loop
    sdinv[t] = dv;
    if (node < N_NODES) {
      rbeg[node] = excl;
      rend[node] = excl + v;
      dinv[node] = dv;
    }
  }
  __syncthreads();
  for (int i = 0; i < ne; ++i) {
    int code = ecache[i];
    int pos = atomicAdd(&lcur[code >> 17], 1);
    csr[pos] = code & SMASK;
  }
  // fused Xs = (x @ C) * dinv for this bucket's 256 nodes
  for (int idx = t; idx < BUCK_NODES * 8; idx += 512) {
    int li = idx >> 3, k = idx & 7;
    int node = (b << BUCK_SHIFT) + li;
    if (node < N_NODES) {
      float s = 0.f;
      for (int c = 0; c < 27; ++c) s += xs[li*27+c] * cst->C[c*8+k];
      Xs[(size_t)node*8+k] = s * sdinv[li];
    }
  }
}

// ------ gather pass 1: software-pipelined csr prefetch -----------------------
__global__ __launch_bounds__(256) void k_gather1(const int* __restrict__ rbeg,
                                                 const int* __restrict__ rend,
                                                 const int* __restrict__ csr,
                                                 const float* __restrict__ dinv,
                                                 const float2* __restrict__ Xs2,
                                                 float2* __restrict__ Ys2,
                                                 float* __restrict__ dvec) {
  int t = blockIdx.x * 256 + threadIdx.x;
  int d = t >> 2, q = t & 3;
  if (d >= N_NODES) return;
  const int beg = rbeg[d], end = rend[d];
  const float nd = dinv[d];
  float2 self = Xs2[d*4 + q];
  float ax = self.x, ay = self.y;
  float dsum = nd;                  // self-loop contribution
  int j = beg;
  if (j + 8 <= end) {
    int s0 = csr[j],   s1 = csr[j+1], s2 = csr[j+2], s3 = csr[j+3];
    int s4 = csr[j+4], s5 = csr[j+5], s6 = csr[j+6], s7 = csr[j+7];
    for (;;) {
      float2 a0 = Xs2[s0*4+q], a1 = Xs2[s1*4+q], a2 = Xs2[s2*4+q], a3 = Xs2[s3*4+q];
      float2 a4 = Xs2[s4*4+q], a5 = Xs2[s5*4+q], a6 = Xs2[s6*4+q], a7 = Xs2[s7*4+q];
      float d0 = 0.f, d1 = 0.f, d2 = 0.f, d3 = 0.f;
      float d4 = 0.f, d5 = 0.f, d6 = 0.f, d7 = 0.f;
      if (q == 0) {
        d0 = dinv[s0]; d1 = dinv[s1]; d2 = dinv[s2]; d3 = dinv[s3];
        d4 = dinv[s4]; d5 = dinv[s5]; d6 = dinv[s6]; d7 = dinv[s7];
      }
      int jn = j + 8;
      bool more = (jn + 8 <= end);
      int u0, u1, u2, u3, u4, u5, u6, u7;
      if (more) {
        u0 = csr[jn];   u1 = csr[jn+1]; u2 = csr[jn+2]; u3 = csr[jn+3];
        u4 = csr[jn+4]; u5 = csr[jn+5]; u6 = csr[jn+6]; u7 = csr[jn+7];
      } else {
        u0 = u1 = u2 = u3 = u4 = u5 = u6 = u7 = 0;
      }
      ax += ((a0.x + a1.x) + (a2.x + a3.x)) + ((a4.x + a5.x) + (a6.x + a7.x));
      ay += ((a0.y + a1.y) + (a2.y + a3.y)) + ((a4.y + a5.y) + (a6.y + a7.y));
      if (q == 0)
        dsum += ((d0 + d1) + (d2 + d3)) + ((d4 + d5) + (d6 + d7));
      j = jn;
      if (!more) break;
      s0 = u0; s1 = u1; s2 = u2; s3 = u3;
      s4 = u4; s5 = u5; s6 = u6; s7 = u7;
    }
  }
  if (j + 4 <= end) {               // 4-wide sub-batch shortens the serial tail
    int a = csr[j], b = csr[j+1], c = csr[j+2], e = csr[j+3];
    float2 p0 = Xs2[a*4+q], p1 = Xs2[b*4+q], p2 = Xs2[c*4+q], p3 = Xs2[e*4+q];
    ax += (p0.x + p1.x) + (p2.x + p3.x);
    ay += (p0.y + p1.y) + (p2.y + p3.y);
    if (q == 0) dsum += (dinv[a] + dinv[b]) + (dinv[c] + dinv[e]);
    j += 4;
  }
  for (; j < end; ++j) {
    int s = csr[j];
    float2 a = Xs2[s*4+q];
    ax += a.x; ay += a.y;
    if (q == 0) dsum += dinv[s];
  }
  float nn = nd * nd;
  Ys2[t] = make_float2(nn * ax, nn * ay);   // = n_d * h1 (pre-scaled for pass 2)
  if (q == 0) dvec[d] = nd * dsum;
}

// ------ gather pass 2 (+bank rows), same software pipeline --------------------
__global__ __launch_bounds__(256) void k_gather2g(const int* __restrict__ rbeg,
                                                  const int* __restrict__ rend,
                                                  const int* __restrict__ csr,
                                                  const float* __restrict__ dinv,
                                                  const float2* __restrict__ Ys2,
                                                  const float* __restrict__ dvec,
                                                  const float* __restrict__ bank,
                                                  const Consts* __restrict__ cst,
                                                  float2* __restrict__ gall2) {
  int t = blockIdx.x * 256 + threadIdx.x;
  int d = t >> 2, q = t & 3;
  if (d >= N_NODES + NB_BANK) return;
  int c0 = 2*q, c1 = 2*q + 1;
  if (d >= N_NODES) {               // bank rows
    int bk = d - N_NODES;
    float sx = cst->vb[c0], sy = cst->vb[c1];
    for (int cc = 0; cc < 27; ++cc) {
      float bv = bank[bk*27+cc];
      sx += bv * cst->Rb[cc*8+c0];
      sy += bv * cst->Rb[cc*8+c1];
    }
    gall2[t] = make_float2(sx, sy);
    return;
  }
  const int beg = rbeg[d], end = rend[d];
  float2 self = Ys2[d*4 + q];
  float ax = self.x, ay = self.y;
  int j = beg;
  if (j + 8 <= end) {
    int s0 = csr[j],   s1 = csr[j+1], s2 = csr[j+2], s3 = csr[j+3];
    int s4 = csr[j+4], s5 = csr[j+5], s6 = csr[j+6], s7 = csr[j+7];
    for (;;) {
      float2 a0 = Ys2[s0*4+q], a1 = Ys2[s1*4+q], a2 = Ys2[s2*4+q], a3 = Ys2[s3*4+q];
      float2 a4 = Ys2[s4*4+q], a5 = Ys2[s5*4+q], a6 = Ys2[s6*4+q], a7 = Ys2[s7*4+q];
      int jn = j + 8;
      bool more = (jn + 8 <= end);
      int u0, u1, u2, u3, u4, u5, u6, u7;
      if (more) {
        u0 = csr[jn];   u1 = csr[jn+1]; u2 = csr[jn+2]; u3 = csr[jn+3];
        u4 = csr[jn+4]; u5 = csr[jn+5]; u6 = csr[jn+6]; u7 = csr[jn+7];
      } else {
        u0 = u1 = u2 = u3 = u4 = u5 = u6 = u7 = 0;
      }
      ax += ((a0.x + a1.x) + (a2.x + a3.x)) + ((a4.x + a5.x) + (a6.x + a7.x));
      ay += ((a0.y + a1.y) + (a2.y + a3.y)) + ((a4.y + a5.y) + (a6.y + a7.y));
      j = jn;
      if (!more) break;
      s0 = u0; s1 = u1; s2 = u2; s3 = u3;
      s4 = u4; s5 = u5; s6 = u6; s7 = u7;
    }
  }
  if (j + 4 <= end) {
    int a = csr[j], b = csr[j+1], c = csr[j+2], e = csr[j+3];
    float2 p0 = Ys2[a*4+q], p1 = Ys2[b*4+q], p2 = Ys2[c*4+q], p3 = Ys2[e*4+q];
    ax += (p0.x + p1.x) + (p2.x + p3.x);
    ay += (p0.y + p1.y) + (p2.y + p3.y);
    j += 4;
  }
  for (; j < end; ++j) {
    float2 a = Ys2[csr[j]*4+q];
    ax += a.x; ay += a.y;
  }
  float nd = dinv[d], dv = dvec[d];
  gall2[t] = make_float2(nd * ax + dv * cst->u[c0] + cst->vg[c0],
                         nd * ay + dv * cst->u[c1] + cst->vg[c1]);
}

// ---------------- online-softmax merge helper --------------------------------
__device__ inline void sm_merge(float4& m1, float4& s1,
                                const float4 m2, const float4 s2) {
  float4 M;
  M.x = fmaxf(m1.x, m2.x); M.y = fmaxf(m1.y, m2.y);
  M.z = fmaxf(m1.z, m2.z); M.w = fmaxf(m1.w, m2.w);
  s1.x = s1.x * expf(m1.x - M.x) + s2.x * expf(m2.x - M.x);
  s1.y = s1.y * expf(m1.y - M.y) + s2.y * expf(m2.y - M.y);
  s1.z = s1.z * expf(m1.z - M.z) + s2.z * expf(m2.z - M.z);
  s1.w = s1.w * expf(m1.w - M.w) + s2.w * expf(m2.w - M.w);
  m1 = M;
}

// ---- pair stats only (no z materialization); 4 pairs/thread, 489 blocks -----
__global__ __launch_bounds__(256) void k_z(const int* __restrict__ node1,
                                           const int* __restrict__ node2,
                                           const float* __restrict__ gall,
                                           float4* __restrict__ bs_m,
                                           float4* __restrict__ bs_s) {
  const int S = NZB4 * 256;
  int p0 = blockIdx.x * 256 + threadIdx.x;
  float4 m = make_float4(-1e30f, -1e30f, -1e30f, -1e30f);
  float4 s = make_float4(0.f, 0.f, 0.f, 0.f);
#pragma unroll
  for (int i = 0; i < 4; ++i) {
    int p = p0 + i * S;
    if (p < N_PAIRS) {
      int n1 = node1[p], n2 = node2[p];
      const float4 a = *(const float4*)(gall + (size_t)n1*8);
      const float4 b = *(const float4*)(gall + (size_t)n2*8 + 4);
      float4 zv = make_float4(a.x+b.x, a.y+b.y, a.z+b.z, a.w+b.w);
      sm_merge(m, s, zv, make_float4(1.f, 1.f, 1.f, 1.f));
    }
  }
  __shared__ float4 lm[256], ls[256];
  lm[threadIdx.x] = m; ls[threadIdx.x] = s;
  __syncthreads();
  for (int st = 128; st > 0; st >>= 1) {
    if (threadIdx.x < st) {
      float4 mm = lm[threadIdx.x], ss = ls[threadIdx.x];
      sm_merge(mm, ss, lm[threadIdx.x + st], ls[threadIdx.x + st]);
      lm[threadIdx.x] = mm; ls[threadIdx.x] = ss;
    }
    __syncthreads();
  }
  if (threadIdx.x == 0) { bs_m[blockIdx.x] = lm[0]; bs_s[blockIdx.x] = ls[0]; }
}

// -- combine stats (redundant per block) + recompute z from gall + normalize --
__global__ __launch_bounds__(256) void k_final(const int* __restrict__ node1,
                                               const int* __restrict__ node2,
                                               const float* __restrict__ gall,
                                               const float4* __restrict__ bs_m,
                                               const float4* __restrict__ bs_s,
                                               float* __restrict__ out) {
  float4 m = make_float4(-1e30f, -1e30f, -1e30f, -1e30f);
  float4 s = make_float4(0.f, 0.f, 0.f, 0.f);
  for (int i = threadIdx.x; i < NZB4; i += 256)
    sm_merge(m, s, bs_m[i], bs_s[i]);
  __shared__ float4 lm[256], ls[256];
  lm[threadIdx.x] = m; ls[threadIdx.x] = s;
  __syncthreads();
  for (int st = 128; st > 0; st >>= 1) {
    if (threadIdx.x < st) {
      float4 mm = lm[threadIdx.x], ss = ls[threadIdx.x];
      sm_merge(mm, ss, lm[threadIdx.x + st], ls[threadIdx.x + st]);
      lm[threadIdx.x] = mm; ls[threadIdx.x] = ss;
    }
    __syncthreads();
  }
  const float4 M = lm[0], S4 = ls[0];
  const float i0 = 1.f / S4.x, i1 = 1.f / S4.y;
  const float i2 = 1.f / S4.z, i3 = 1.f / S4.w;
  const int S = NZB4 * 256;
  int p0 = blockIdx.x * 256 + threadIdx.x;
#pragma unroll
  for (int i = 0; i < 4; ++i) {
    int p = p0 + i * S;
    if (p < N_PAIRS) {
      int n1 = node1[p], n2 = node2[p];
      const float4 a = *(const float4*)(gall + (size_t)n1*8);
      const float4 b = *(const float4*)(gall + (size_t)n2*8 + 4);
      float4 zv = make_float4(a.x+b.x, a.y+b.y, a.z+b.z, a.w+b.w);
      float4 o = make_float4(expf(zv.x - M.x) * i0, expf(zv.y - M.y) * i1,
                             expf(zv.z - M.z) * i2, expf(zv.w - M.w) * i3);
      ((float4*)out)[p] = o;
    }
  }
}

extern "C" void kernel_launch(void* const* d_in, const int* in_sizes, int n_in,
                              void* d_out, int out_size, void* d_ws, size_t ws_size,
                              hipStream_t stream) {
  const float* x    = (const float*)d_in[0];
  const float* bank = (const float*)d_in[1];
  const float* W1   = (const float*)d_in[2];
  const float* b1   = (const float*)d_in[3];
  const float* W2   = (const float*)d_in[4];
  const float* b2   = (const float*)d_in[5];
  const float* Wb   = (const float*)d_in[6];
  const float* bb   = (const float*)d_in[7];
  const float* Wf1  = (const float*)d_in[8];
  const float* bf1  = (const float*)d_in[9];
  const float* Wf2  = (const float*)d_in[10];
  const float* bf2  = (const float*)d_in[11];
  const float* Wf3  = (const float*)d_in[12];
  const float* bf3  = (const float*)d_in[13];
  const int* ei     = (const int*)d_in[14];
  const int* node1  = (const int*)d_in[15];
  const int* node2  = (const int*)d_in[16];
  float* out = (float*)d_out;

  char* w = (char*)d_ws;
  size_t off = 0;
  auto take = [&](size_t bytes) -> char* {
    char* p = w + off;
    off = (off + bytes + 255) & ~(size_t)255;
    return p;
  };
  Consts* cst    = (Consts*)take(sizeof(Consts));
  int*    bcnt   = (int*)take(NBUCK * 4);
  float*  dinv   = (float*)take(N_NODES * 4);
  int*    rbeg   = (int*)take(N_NODES * 4);
  int*    rend   = (int*)take(N_NODES * 4);
  int*    csr    = (int*)take((size_t)NBUCK * BCAP * 4);
  float*  Xs     = (float*)take((size_t)N_NODES * 8 * 4);
  float*  Ys     = (float*)take((size_t)N_NODES * 8 * 4);
  float*  dvec   = (float*)take(N_NODES * 4);
  float*  gall   = (float*)take((size_t)(N_NODES + NB_BANK) * 8 * 4);
  int*    ebuf   = (int*)take((size_t)NBUCK * BCAP * 4);
  float4* bs_m   = (float4*)take((size_t)NZB4 * 16);
  float4* bs_s   = (float4*)take((size_t)NZB4 * 16);

  hipMemsetAsync(bcnt, 0, NBUCK * 4, stream);

  // single-pass bucket scatter + (extra block) weight-chain precompute
  k_scatter<<<NSCAT + 1, 1024, 0, stream>>>(ei, bcnt, ebuf, W1, b1, W2, b2,
                                            Wb, bb, Wf1, bf1, Wf2, bf2,
                                            Wf3, bf3, cst);
  // per-bucket: degree/dinv/rbeg/rend + CSR fill + fused Xs compute
  k_degfill_x8<<<NBUCK, 512, 0, stream>>>(bcnt, ebuf, x, cst,
                                          dinv, rbeg, rend, csr, Xs);
  // propagation (software-pipelined csr prefetch, unroll-8 + 4-wide sub-batch)
  k_gather1<<<(N_NODES * 4 + 255) / 256, 256, 0, stream>>>(
      rbeg, rend, csr, dinv, (const float2*)Xs, (float2*)Ys, dvec);
  k_gather2g<<<((N_NODES + NB_BANK) * 4 + 255) / 256, 256, 0, stream>>>(
      rbeg, rend, csr, dinv, (const float2*)Ys, dvec, bank, cst, (float2*)gall);
  // pair phase: stats only, then combine+recompute-z+normalize (no z buffer)
  k_z<<<NZB4, 256, 0, stream>>>(node1, node2, gall, bs_m, bs_s);
  k_final<<<NZB4, 256, 0, stream>>>(node1, node2, gall, bs_m, bs_s, out);
}